// Round 20
// baseline (253.368 us; speedup 1.0000x reference)
//
#include <hip/hip_runtime.h>
#include <hip/hip_bf16.h>

typedef __attribute__((ext_vector_type(8))) short short8;
typedef __attribute__((ext_vector_type(4))) float f32x4;

// A matrix layout: [50048][1152] bf16. Cols 0..1023 = z (k' = d*8+r order),
// cols 1024..1151 = y (LN+GELU activations). Row stride 1152 elems = 2304 B.
#define LDA 1152
// Counters padded to one per 64B cacheline (stride 16 ints) to kill
// intra-line atomic serialization in hist/scatter.
#define CPAD 16

__device__ __forceinline__ float bf2f(unsigned short u) {
    union { unsigned int i; float f; } v; v.i = ((unsigned int)u) << 16; return v.f;
}
__device__ __forceinline__ unsigned short f2bf(float f) {
    __hip_bfloat16 h = __float2bfloat16(f);
    union { __hip_bfloat16 h; unsigned short u; } v; v.h = h; return v.u;
}
__device__ __forceinline__ float gelu_exact(float t) {
    return 0.5f * t * (1.0f + erff(t * 0.70710678118654752f));
}

// ---------------------------------------------------------------------------
// prep_all: three independent jobs in one dispatch.
//   blocks [0, 1152)            : pack B1,B2 -> MFMA fragment order
//   blocks [1152, 1152+cntB)    : zero padded cnt[] histogram (3.2MB)
//   blocks [1152+cntB, ...)     : LN+GELU of x -> A tail cols 1024..1151
// ---------------------------------------------------------------------------
__global__ void prep_all(const float* __restrict__ W1, const float* __restrict__ root1,
                         unsigned short* __restrict__ Bf1,
                         const float* __restrict__ W2, const float* __restrict__ root2,
                         unsigned short* __restrict__ Bf2,
                         int* __restrict__ cnt, int cntN,
                         const float* __restrict__ x, const float* __restrict__ g,
                         const float* __restrict__ bvec, unsigned short* __restrict__ A,
                         int N) {
    int b = blockIdx.x;
    if (b < 1152) {
        int i = b * 256 + threadIdx.x;
        const float* W = W1; const float* root = root1; unsigned short* Bfrag = Bf1;
        if (i >= 1152 * 128) { i -= 1152 * 128; W = W2; root = root2; Bfrag = Bf2; }
        int kp = i >> 7, n = i & 127;
        float v;
        if (kp < 1024) {
            int d = kp >> 3, r = kp & 7;
            v = W[((size_t)r * 128 + d) * 128 + n];
        } else {
            v = root[(size_t)(kp - 1024) * 128 + n];
        }
        int kb = kp >> 5;
        int lane = (((kp >> 3) & 3) << 4) | (n & 15);
        int j = kp & 7;
        int t = n >> 4;
        Bfrag[(((size_t)(kb * 8 + t) * 64 + lane) << 3) + j] = f2bf(v);
        return;
    }
    int cntB = (cntN + 255) >> 8;
    if (b < 1152 + cntB) {
        int zi = (b - 1152) * 256 + threadIdx.x;
        if (zi < cntN) cnt[zi] = 0;
        return;
    }
    // ln_gelu part
    int row = (((b - 1152 - cntB) * 256) + threadIdx.x) >> 6;
    if (row >= N) return;
    int lane = threadIdx.x & 63;
    float2 v = *(const float2*)(x + (size_t)row * 128 + lane * 2);
    float s = v.x + v.y;
    #pragma unroll
    for (int o = 32; o; o >>= 1) s += __shfl_xor(s, o);
    float mu = s * (1.0f / 128.0f);
    float d0 = v.x - mu, d1 = v.y - mu;
    float q = d0 * d0 + d1 * d1;
    #pragma unroll
    for (int o = 32; o; o >>= 1) q += __shfl_xor(q, o);
    float rs = rsqrtf(q * (1.0f / 128.0f) + 1e-5f);
    float2 gg = *(const float2*)(g + lane * 2);
    float2 bb = *(const float2*)(bvec + lane * 2);
    ushort2 o2;
    o2.x = f2bf(gelu_exact(d0 * rs * gg.x + bb.x));
    o2.y = f2bf(gelu_exact(d1 * rs * gg.y + bb.y));
    *(ushort2*)(A + (size_t)row * LDA + 1024 + lane * 2) = o2;
}

// ---------------------------------------------------------------------------
// CSR build (padded counters)
// ---------------------------------------------------------------------------
__global__ void hist_dst(const int* __restrict__ ei, int* __restrict__ cnt, int E) {
    int e = blockIdx.x * 256 + threadIdx.x;
    if (e >= E) return;
    atomicAdd(&cnt[ei[E + e] * CPAD], 1);
}

// block-of-256 exclusive scan over padded cnt; part[i] dense, bsum[blk] total
__global__ void scan1(const int* __restrict__ cnt, int* __restrict__ part,
                      int* __restrict__ bsum, int N) {
    int i = blockIdx.x * 256 + threadIdx.x;
    int v = (i < N) ? cnt[i * CPAD] : 0;
    int lane = threadIdx.x & 63, wid = threadIdx.x >> 6;
    int s = v;
    #pragma unroll
    for (int off = 1; off < 64; off <<= 1) {
        int t = __shfl_up(s, off);
        if (lane >= off) s += t;
    }
    __shared__ int wsum[4];
    if (lane == 63) wsum[wid] = s;
    __syncthreads();
    int add = 0;
    for (int w = 0; w < wid; ++w) add += wsum[w];
    s += add;
    part[i] = s - v;
    if (threadIdx.x == 255) bsum[blockIdx.x] = s;
}

// scan3: block b computes base = sum(bsum[0..b)); rowptr dense, woff padded.
__global__ void scan3(const int* __restrict__ part, const int* __restrict__ bsum,
                      int* __restrict__ rowptr, int* __restrict__ woff, int N) {
    __shared__ int base_sh;
    int b = blockIdx.x;
    if (threadIdx.x < 64) {
        int acc = 0;
        for (int j = threadIdx.x; j < b; j += 64) acc += bsum[j];
        #pragma unroll
        for (int o = 32; o; o >>= 1) acc += __shfl_xor(acc, o);
        if (threadIdx.x == 0) base_sh = acc;
    }
    __syncthreads();
    int i = b * 256 + threadIdx.x;
    if (i >= N) return;
    int v = part[i] + base_sh;
    rowptr[i] = v;
    woff[i * CPAD] = v;
}

// Light scatter: ONE 8-byte scattered store per edge — (src, original id).
// attr is permuted into CSR order by permute_attr (sequential writes there).
__global__ void scatter_edges(const int* __restrict__ ei, int* __restrict__ woff,
                              int2* __restrict__ esp, int E) {
    int e = blockIdx.x * 256 + threadIdx.x;
    if (e >= E) return;
    int src = ei[e], dst = ei[E + e];
    int p = atomicAdd(&woff[dst * CPAD], 1);
    int2 v; v.x = src; v.y = e;
    esp[p] = v;
}

// Build eattr in CSR order: sequential esp read, random attr gather (once),
// sequential bf16x8 write. Consumers then stream eattr sequentially (R18 fix).
__global__ void permute_attr(const int2* __restrict__ esp, const float4* __restrict__ attr,
                             short8* __restrict__ eattr, int E) {
    int p = blockIdx.x * 256 + threadIdx.x;
    if (p >= E) return;
    int e = esp[p].y;
    float4 a0 = attr[2 * e], a1 = attr[2 * e + 1];
    short8 pk;
    pk[0] = (short)f2bf(a0.x); pk[1] = (short)f2bf(a0.y);
    pk[2] = (short)f2bf(a0.z); pk[3] = (short)f2bf(a0.w);
    pk[4] = (short)f2bf(a1.x); pk[5] = (short)f2bf(a1.y);
    pk[6] = (short)f2bf(a1.z); pk[7] = (short)f2bf(a1.w);
    eattr[p] = pk;
}

// ---------------------------------------------------------------------------
// Edge aggregation into A cols 0..1023 (k'-ordered). One wave per dst node;
// gathers y from A tail; esp/eattr read sequentially (CSR order).
// Unrolled x4 (4 gathers in flight). (R9/R13/R15-proven structure.)
// ---------------------------------------------------------------------------
__global__ __launch_bounds__(256) void edge_z(const int* __restrict__ rowptr,
                                              const int2* __restrict__ esp,
                                              const short8* __restrict__ eattr,
                                              unsigned short* __restrict__ A, int N, int E) {
    int row = (blockIdx.x << 2) + (threadIdx.x >> 6);
    if (row >= N) return;
    int lane = threadIdx.x & 63;
    int e0 = rowptr[row];
    int e1 = (row + 1 < N) ? rowptr[row + 1] : E;
    float a0[8] = {0,0,0,0,0,0,0,0};
    float a1[8] = {0,0,0,0,0,0,0,0};
    const unsigned short* yl = A + 1024 + lane * 2;

    #define EDGE_FMA(hv, ea) do {                                      \
        float y0 = bf2f((unsigned short)((hv) & 0xffffu));             \
        float y1 = bf2f((unsigned short)((hv) >> 16));                 \
        _Pragma("unroll")                                              \
        for (int r = 0; r < 8; ++r) {                                  \
            float wv = bf2f((unsigned short)(ea)[r]);                  \
            a0[r] += wv * y0; a1[r] += wv * y1;                        \
        }                                                              \
    } while (0)

    int e = e0;
    for (; e + 4 <= e1; e += 4) {
        unsigned int h[4];
        short8 ea[4];
        #pragma unroll
        for (int u = 0; u < 4; ++u) {
            h[u] = *(const unsigned int*)(yl + (size_t)esp[e + u].x * LDA);
            ea[u] = eattr[e + u];
        }
        #pragma unroll
        for (int u = 0; u < 4; ++u) EDGE_FMA(h[u], ea[u]);
    }
    for (; e < e1; ++e) {
        unsigned int h = *(const unsigned int*)(yl + (size_t)esp[e].x * LDA);
        short8 ea = eattr[e];
        EDGE_FMA(h, ea);
    }
    #undef EDGE_FMA

    short8 p0, p1;
    #pragma unroll
    for (int r = 0; r < 8; ++r) { p0[r] = (short)f2bf(a0[r]); p1[r] = (short)f2bf(a1[r]); }
    unsigned short* zr = A + (size_t)row * LDA + lane * 16;
    *(short8*)zr = p0;
    *(short8*)(zr + 8) = p1;
}

// ---------------------------------------------------------------------------
// GEMM v8 (R13/R15-proven) + T5 setprio: A (N x 1152 bf16) @ B (1152 x 128).
// Counted-vmcnt pipeline with pinned VMEM issue order.
// Block = 256 threads (4 waves); wave = 16 rows x 128 cols; grid = 782 blocks.
// Per chunk c: STAGE(c+1) [4 gload_lds] | sched_barrier | A-loads(c+1) [2 reg
// loads, NEWEST] | sched_barrier | setprio(1) MFMA(c) setprio(0) | vmcnt(2)
// [in-order retire => stage drained; A-loads fly across the barrier] | s_barrier.
// MODE 0: gelu(LN(C+bias)) -> bf16 into A tail (own rows only).
// MODE 1: C+bias+xres -> fp32 out [N][128].
// ---------------------------------------------------------------------------
template <int MODE>
__global__ __launch_bounds__(256) void gemm_fused(
        unsigned short* __restrict__ A, const unsigned short* __restrict__ Bfrag,
        const float* __restrict__ bias, const float* __restrict__ lng,
        const float* __restrict__ lnb, const float* __restrict__ xres,
        float* __restrict__ outp, int N) {
    __shared__ short8 Bs[2][1024];   // 2 x 16 KB

    int w = threadIdx.x >> 6;        // 0..3
    int lane = threadIdx.x & 63;
    int l15 = lane & 15, lhi = lane >> 4;
    int m0 = blockIdx.x * 64 + w * 16;

    const unsigned short* ap = A + (size_t)(m0 + l15) * LDA + lhi * 8;
    const short8* bfb = (const short8*)Bfrag;

    // stage chunk c (kb = 2c, 2c+1) = 1024 short8 = 16KB; 4 gload_lds per thread
    #define STAGE(buf, c)                                                          \
        do {                                                                       \
            const short8* gsrc = bfb + (size_t)(c) * 1024 + w * 64;                \
            _Pragma("unroll")                                                      \
            for (int i = 0; i < 4; ++i)                                            \
                __builtin_amdgcn_global_load_lds(&gsrc[i * 256 + lane],            \
                                                 &Bs[buf][w * 64 + i * 256], 16, 0, 0); \
        } while (0)

    #define BARRIER_CNT2()                                                          \
        do {                                                                        \
            asm volatile("s_waitcnt vmcnt(2)" ::: "memory");                        \
            __builtin_amdgcn_sched_barrier(0);                                      \
            __builtin_amdgcn_s_barrier();                                           \
            __builtin_amdgcn_sched_barrier(0);                                      \
        } while (0)

    short8 af[2], afn[2];
    STAGE(0, 0);                                   // 4 VMEM (oldest)
    __builtin_amdgcn_sched_barrier(0);
    #pragma unroll
    for (int k = 0; k < 2; ++k) af[k] = *(const short8*)(ap + k * 32);  // 2 newest
    __builtin_amdgcn_sched_barrier(0);
    BARRIER_CNT2();                                // stage(0) visible; A(0) in flight

    f32x4 acc[8] = {};
    for (int c = 0; c < 18; ++c) {
        int cur = c & 1;
        if (c < 17) {
            STAGE(cur ^ 1, c + 1);                 // 4 VMEM
            __builtin_amdgcn_sched_barrier(0);
            #pragma unroll
            for (int k = 0; k < 2; ++k)            // 2 VMEM (newest before wait)
                afn[k] = *(const short8*)(ap + ((c + 1) * 2 + k) * 32);
            __builtin_amdgcn_sched_barrier(0);
        }
        __builtin_amdgcn_s_setprio(1);
        #pragma unroll
        for (int k = 0; k < 2; ++k) {
            #pragma unroll
            for (int t = 0; t < 8; ++t) {
                short8 b = Bs[cur][k * 512 + t * 64 + lane];
                acc[t] = __builtin_amdgcn_mfma_f32_16x16x32_bf16(af[k], b, acc[t], 0, 0, 0);
            }
        }
        __builtin_amdgcn_s_setprio(0);
        if (c < 17) {
            BARRIER_CNT2();                        // drain stage(c+1); A(c+1) flies on
            af[0] = afn[0]; af[1] = afn[1];
        }
    }
    #undef STAGE
    #undef BARRIER_CNT2

    float bcol[8];
    #pragma unroll
    for (int t = 0; t < 8; ++t) bcol[t] = bias[t * 16 + l15];

    if (MODE == 0) {
        float gcol[8], lbcol[8];
        #pragma unroll
        for (int t = 0; t < 8; ++t) { gcol[t] = lng[t * 16 + l15]; lbcol[t] = lnb[t * 16 + l15]; }
        #pragma unroll
        for (int reg = 0; reg < 4; ++reg) {
            int row = m0 + lhi * 4 + reg;
            float tv[8];
            float s = 0.f;
            #pragma unroll
            for (int t = 0; t < 8; ++t) { tv[t] = acc[t][reg] + bcol[t]; s += tv[t]; }
            #pragma unroll
            for (int msk = 1; msk < 16; msk <<= 1) s += __shfl_xor(s, msk);
            float mu = s * (1.0f / 128.0f);
            float q = 0.f;
            #pragma unroll
            for (int t = 0; t < 8; ++t) { float d = tv[t] - mu; q += d * d; }
            #pragma unroll
            for (int msk = 1; msk < 16; msk <<= 1) q += __shfl_xor(q, msk);
            float rs = rsqrtf(q * (1.0f / 128.0f) + 1e-5f);
            if (row < N) {
                #pragma unroll
                for (int t = 0; t < 8; ++t) {
                    float u = gelu_exact((tv[t] - mu) * rs * gcol[t] + lbcol[t]);
                    A[(size_t)row * LDA + 1024 + t * 16 + l15] = f2bf(u);
                }
            }
        }
    } else {
        #pragma unroll
        for (int reg = 0; reg < 4; ++reg) {
            int row = m0 + lhi * 4 + reg;
            if (row < N) {
                #pragma unroll
                for (int t = 0; t < 8; ++t) {
                    size_t idx = (size_t)row * 128 + t * 16 + l15;
                    outp[idx] = acc[t][reg] + bcol[t] + xres[idx];
                }
            }
        }
    }
}

extern "C" void kernel_launch(void* const* d_in, const int* in_sizes, int n_in,
                              void* d_out, int out_size, void* d_ws, size_t ws_size,
                              hipStream_t stream) {
    const float* x     = (const float*)d_in[0];
    const int*   ei    = (const int*)d_in[1];
    const float* attr  = (const float*)d_in[2];
    const float* ln1g  = (const float*)d_in[3];
    const float* ln1b  = (const float*)d_in[4];
    const float* W1    = (const float*)d_in[5];
    const float* root1 = (const float*)d_in[6];
    const float* b1    = (const float*)d_in[7];
    const float* ln2g  = (const float*)d_in[8];
    const float* ln2b  = (const float*)d_in[9];
    const float* W2    = (const float*)d_in[10];
    const float* root2 = (const float*)d_in[11];
    const float* b2    = (const float*)d_in[12];

    const int N = in_sizes[0] / 128;   // 50000
    const int E = in_sizes[1] / 2;     // 600000

    // workspace layout; A padded to 50048 rows (782 blocks x 64) for OOB-safe
    // A-frag reads. cnt/woff padded: one counter per 64B line (50176*16 ints).
    char* ws = (char*)d_ws;
    unsigned short* A     = (unsigned short*)(ws);                    // 115,310,592
    unsigned short* Bf1   = (unsigned short*)(ws + 115400000);        // 294,912
    unsigned short* Bf2   = (unsigned short*)(ws + 115700000);        // 294,912
    int*            cnt   = (int*)(ws + 116000000);                   // 3,211,264
    int*            part  = (int*)(ws + 119220000);                   // 200,704
    int*            bsum  = (int*)(ws + 119430000);                   // 1,024
    int*            rowptr= (int*)(ws + 119440000);                   // 200,000
    int*            woff  = (int*)(ws + 119650000);                   // 3,211,264
    int2*           esp   = (int2*)(ws + 122870000);                  // 4,800,000
    short8*         eattr = (short8*)(ws + 127680000);                // 9,600,000

    const int scanBlocks  = (N + 255) / 256;               // 196
    const int edgeBlocksE = (E + 255) / 256;               // 2344
    const int rowsBlocks  = (N * 64 + 255) / 256;          // 12500
    const int nodeBlocks  = (N + 3) / 4;                   // 12500
    const int gemmBlocks  = (N + 63) / 64;                 // 782
    const int cntN        = scanBlocks * 256 * CPAD;       // 802,816 ints
    const int cntB        = (cntN + 255) / 256;            // 3136
    const int prepBlocks  = 1152 + cntB + rowsBlocks;

    // pack weights + zero padded histogram + layer-1 LN/GELU, one dispatch
    prep_all<<<prepBlocks, 256, 0, stream>>>(W1, root1, Bf1, W2, root2, Bf2,
                                             cnt, cntN,
                                             x, ln1g, ln1b, A, N);

    // CSR build (by dst), padded counters
    hist_dst<<<edgeBlocksE, 256, 0, stream>>>(ei, cnt, E);
    scan1<<<scanBlocks, 256, 0, stream>>>(cnt, part, bsum, N);
    scan3<<<scanBlocks, 256, 0, stream>>>(part, bsum, rowptr, woff, N);
    scatter_edges<<<edgeBlocksE, 256, 0, stream>>>(ei, woff, esp, E);
    permute_attr<<<edgeBlocksE, 256, 0, stream>>>(esp, (const float4*)attr, eattr, E);

    // ---- layer 1 ----
    edge_z<<<nodeBlocks, 256, 0, stream>>>(rowptr, esp, eattr, A, N, E);
    gemm_fused<0><<<gemmBlocks, 256, 0, stream>>>(A, Bf1, b1, ln2g, ln2b, nullptr, nullptr, N);

    // ---- layer 2 ----
    edge_z<<<nodeBlocks, 256, 0, stream>>>(rowptr, esp, eattr, A, N, E);
    gemm_fused<1><<<gemmBlocks, 256, 0, stream>>>(A, Bf2, b2, nullptr, nullptr, x, (float*)d_out, N);
}

// Round 21
// 241.601 us; speedup vs baseline: 1.0487x; 1.0487x over previous
//
#include <hip/hip_runtime.h>
#include <hip/hip_bf16.h>

typedef __attribute__((ext_vector_type(8))) short short8;
typedef __attribute__((ext_vector_type(4))) float f32x4;

// A matrix layout: [50048][1152] bf16. Cols 0..1023 = z (k' = d*8+r order),
// cols 1024..1151 = y (LN+GELU activations). Row stride 1152 elems = 2304 B.
#define LDA 1152

__device__ __forceinline__ float bf2f(unsigned short u) {
    union { unsigned int i; float f; } v; v.i = ((unsigned int)u) << 16; return v.f;
}
__device__ __forceinline__ unsigned short f2bf(float f) {
    __hip_bfloat16 h = __float2bfloat16(f);
    union { __hip_bfloat16 h; unsigned short u; } v; v.h = h; return v.u;
}
__device__ __forceinline__ float gelu_exact(float t) {
    return 0.5f * t * (1.0f + erff(t * 0.70710678118654752f));
}

// ---------------------------------------------------------------------------
// prep_all: three independent jobs in one dispatch (saves launch gaps).
//   blocks [0, 1152)            : pack B1,B2 -> MFMA fragment order
//   blocks [1152, 1152+cntB)    : zero cnt[] histogram
//   blocks [1152+cntB, ...)     : LN+GELU of x -> A tail cols 1024..1151
// B-pack: k' = d*8 + r (k'<1024), k' = 1024+d for root;
//   Bfrag[((kb*8+t)*64+lane)*8+j] = B[k'][n], kb=k'>>5,
//   lane=((k'>>3)&3)<<4 | (n&15), j=k'&7, t=n>>4.
// ---------------------------------------------------------------------------
__global__ void prep_all(const float* __restrict__ W1, const float* __restrict__ root1,
                         unsigned short* __restrict__ Bf1,
                         const float* __restrict__ W2, const float* __restrict__ root2,
                         unsigned short* __restrict__ Bf2,
                         int* __restrict__ cnt, int cntB,
                         const float* __restrict__ x, const float* __restrict__ g,
                         const float* __restrict__ bvec, unsigned short* __restrict__ A,
                         int N) {
    int b = blockIdx.x;
    if (b < 1152) {
        int i = b * 256 + threadIdx.x;
        const float* W = W1; const float* root = root1; unsigned short* Bfrag = Bf1;
        if (i >= 1152 * 128) { i -= 1152 * 128; W = W2; root = root2; Bfrag = Bf2; }
        int kp = i >> 7, n = i & 127;
        float v;
        if (kp < 1024) {
            int d = kp >> 3, r = kp & 7;
            v = W[((size_t)r * 128 + d) * 128 + n];
        } else {
            v = root[(size_t)(kp - 1024) * 128 + n];
        }
        int kb = kp >> 5;
        int lane = (((kp >> 3) & 3) << 4) | (n & 15);
        int j = kp & 7;
        int t = n >> 4;
        Bfrag[(((size_t)(kb * 8 + t) * 64 + lane) << 3) + j] = f2bf(v);
        return;
    }
    if (b < 1152 + cntB) {
        int zi = (b - 1152) * 256 + threadIdx.x;
        cnt[zi] = 0;
        return;
    }
    // ln_gelu part
    int row = (((b - 1152 - cntB) * 256) + threadIdx.x) >> 6;
    if (row >= N) return;
    int lane = threadIdx.x & 63;
    float2 v = *(const float2*)(x + (size_t)row * 128 + lane * 2);
    float s = v.x + v.y;
    #pragma unroll
    for (int o = 32; o; o >>= 1) s += __shfl_xor(s, o);
    float mu = s * (1.0f / 128.0f);
    float d0 = v.x - mu, d1 = v.y - mu;
    float q = d0 * d0 + d1 * d1;
    #pragma unroll
    for (int o = 32; o; o >>= 1) q += __shfl_xor(q, o);
    float rs = rsqrtf(q * (1.0f / 128.0f) + 1e-5f);
    float2 gg = *(const float2*)(g + lane * 2);
    float2 bb = *(const float2*)(bvec + lane * 2);
    ushort2 o2;
    o2.x = f2bf(gelu_exact(d0 * rs * gg.x + bb.x));
    o2.y = f2bf(gelu_exact(d1 * rs * gg.y + bb.y));
    *(ushort2*)(A + (size_t)row * LDA + 1024 + lane * 2) = o2;
}

// ---------------------------------------------------------------------------
// CSR build
// ---------------------------------------------------------------------------
__global__ void hist_dst(const int* __restrict__ ei, int* __restrict__ cnt, int E) {
    int e = blockIdx.x * 256 + threadIdx.x;
    if (e >= E) return;
    atomicAdd(&cnt[ei[E + e]], 1);
}

// block-of-256 exclusive scan; part[i] = excl within block, bsum[blk] = block total
__global__ void scan1(const int* __restrict__ cnt, int* __restrict__ part,
                      int* __restrict__ bsum, int N) {
    int i = blockIdx.x * 256 + threadIdx.x;
    int v = (i < N) ? cnt[i] : 0;
    int lane = threadIdx.x & 63, wid = threadIdx.x >> 6;
    int s = v;
    #pragma unroll
    for (int off = 1; off < 64; off <<= 1) {
        int t = __shfl_up(s, off);
        if (lane >= off) s += t;
    }
    __shared__ int wsum[4];
    if (lane == 63) wsum[wid] = s;
    __syncthreads();
    int add = 0;
    for (int w = 0; w < wid; ++w) add += wsum[w];
    s += add;
    part[i] = s - v;
    if (threadIdx.x == 255) bsum[blockIdx.x] = s;
}

// scan3: block b computes base = sum(bsum[0..b)) itself, then
// rowptr[i] = part[i] + base. (No separate scan2 dispatch.)
__global__ void scan3(const int* __restrict__ part, const int* __restrict__ bsum,
                      int* __restrict__ rowptr, int* __restrict__ woff, int N) {
    __shared__ int base_sh;
    int b = blockIdx.x;
    if (threadIdx.x < 64) {
        int acc = 0;
        for (int j = threadIdx.x; j < b; j += 64) acc += bsum[j];
        #pragma unroll
        for (int o = 32; o; o >>= 1) acc += __shfl_xor(acc, o);
        if (threadIdx.x == 0) base_sh = acc;
    }
    __syncthreads();
    int i = b * 256 + threadIdx.x;
    if (i >= N) return;
    int v = part[i] + base_sh;
    rowptr[i] = v;
    woff[i] = v;
}

// eattr stored bf16-packed IN CSR ORDER: 8 relations -> 16B per edge.
// (R18/R20 lesson: pay the permutation once here, in the scatter itself;
// per-layer consumers must read eattr sequentially.)
__global__ void scatter_edges(const int* __restrict__ ei, const float4* __restrict__ attr,
                              int* __restrict__ woff, int* __restrict__ esrc,
                              short8* __restrict__ eattr, int E) {
    int e = blockIdx.x * 256 + threadIdx.x;
    if (e >= E) return;
    int src = ei[e], dst = ei[E + e];
    float4 a0 = attr[2 * e], a1 = attr[2 * e + 1];
    short8 pk;
    pk[0] = (short)f2bf(a0.x); pk[1] = (short)f2bf(a0.y);
    pk[2] = (short)f2bf(a0.z); pk[3] = (short)f2bf(a0.w);
    pk[4] = (short)f2bf(a1.x); pk[5] = (short)f2bf(a1.y);
    pk[6] = (short)f2bf(a1.z); pk[7] = (short)f2bf(a1.w);
    int p = atomicAdd(&woff[dst], 1);
    esrc[p] = src;
    eattr[p] = pk;
}

// ---------------------------------------------------------------------------
// Edge aggregation into A cols 0..1023 (k'-ordered). One wave per dst node;
// gathers y from A tail; eattr/esrc read sequentially (CSR order).
// Unrolled x4 (4 gathers in flight). (R9/R13/R15/R19-proven: 47 us, VGPR 32.)
// ---------------------------------------------------------------------------
__global__ __launch_bounds__(256) void edge_z(const int* __restrict__ rowptr,
                                              const int* __restrict__ esrc,
                                              const short8* __restrict__ eattr,
                                              unsigned short* __restrict__ A, int N, int E) {
    int row = (blockIdx.x << 2) + (threadIdx.x >> 6);
    if (row >= N) return;
    int lane = threadIdx.x & 63;
    int e0 = rowptr[row];
    int e1 = (row + 1 < N) ? rowptr[row + 1] : E;
    float a0[8] = {0,0,0,0,0,0,0,0};
    float a1[8] = {0,0,0,0,0,0,0,0};
    const unsigned short* yl = A + 1024 + lane * 2;

    #define EDGE_FMA(hv, ea) do {                                      \
        float y0 = bf2f((unsigned short)((hv) & 0xffffu));             \
        float y1 = bf2f((unsigned short)((hv) >> 16));                 \
        _Pragma("unroll")                                              \
        for (int r = 0; r < 8; ++r) {                                  \
            float wv = bf2f((unsigned short)(ea)[r]);                  \
            a0[r] += wv * y0; a1[r] += wv * y1;                        \
        }                                                              \
    } while (0)

    int e = e0;
    for (; e + 4 <= e1; e += 4) {
        unsigned int h[4];
        short8 ea[4];
        #pragma unroll
        for (int u = 0; u < 4; ++u) {
            h[u] = *(const unsigned int*)(yl + (size_t)esrc[e + u] * LDA);
            ea[u] = eattr[e + u];
        }
        #pragma unroll
        for (int u = 0; u < 4; ++u) EDGE_FMA(h[u], ea[u]);
    }
    for (; e < e1; ++e) {
        unsigned int h = *(const unsigned int*)(yl + (size_t)esrc[e] * LDA);
        short8 ea = eattr[e];
        EDGE_FMA(h, ea);
    }
    #undef EDGE_FMA

    short8 p0, p1;
    #pragma unroll
    for (int r = 0; r < 8; ++r) { p0[r] = (short)f2bf(a0[r]); p1[r] = (short)f2bf(a1[r]); }
    unsigned short* zr = A + (size_t)row * LDA + lane * 16;
    *(short8*)zr = p0;
    *(short8*)(zr + 8) = p1;
}

// ---------------------------------------------------------------------------
// GEMM v8 (R13/R15/R19-proven) + T5 setprio: A (N x 1152 bf16) @ B (1152x128).
// Counted-vmcnt pipeline with pinned VMEM issue order.
// Block = 256 threads (4 waves); wave = 16 rows x 128 cols; grid = 782 blocks.
// Per chunk c: STAGE(c+1) [4 gload_lds] | sched_barrier | A-loads(c+1) [2 reg
// loads, NEWEST] | sched_barrier | setprio(1) MFMA(c) setprio(0) | vmcnt(2)
// [in-order retire => stage drained; A-loads fly across the barrier] | s_barrier.
// MODE 0: gelu(LN(C+bias)) -> bf16 into A tail (own rows only).
// MODE 1: C+bias+xres -> fp32 out [N][128].
// ---------------------------------------------------------------------------
template <int MODE>
__global__ __launch_bounds__(256) void gemm_fused(
        unsigned short* __restrict__ A, const unsigned short* __restrict__ Bfrag,
        const float* __restrict__ bias, const float* __restrict__ lng,
        const float* __restrict__ lnb, const float* __restrict__ xres,
        float* __restrict__ outp, int N) {
    __shared__ short8 Bs[2][1024];   // 2 x 16 KB

    int w = threadIdx.x >> 6;        // 0..3
    int lane = threadIdx.x & 63;
    int l15 = lane & 15, lhi = lane >> 4;
    int m0 = blockIdx.x * 64 + w * 16;

    const unsigned short* ap = A + (size_t)(m0 + l15) * LDA + lhi * 8;
    const short8* bfb = (const short8*)Bfrag;

    // stage chunk c (kb = 2c, 2c+1) = 1024 short8 = 16KB; 4 gload_lds per thread
    #define STAGE(buf, c)                                                          \
        do {                                                                       \
            const short8* gsrc = bfb + (size_t)(c) * 1024 + w * 64;                \
            _Pragma("unroll")                                                      \
            for (int i = 0; i < 4; ++i)                                            \
                __builtin_amdgcn_global_load_lds(&gsrc[i * 256 + lane],            \
                                                 &Bs[buf][w * 64 + i * 256], 16, 0, 0); \
        } while (0)

    #define BARRIER_CNT2()                                                          \
        do {                                                                        \
            asm volatile("s_waitcnt vmcnt(2)" ::: "memory");                        \
            __builtin_amdgcn_sched_barrier(0);                                      \
            __builtin_amdgcn_s_barrier();                                           \
            __builtin_amdgcn_sched_barrier(0);                                      \
        } while (0)

    short8 af[2], afn[2];
    STAGE(0, 0);                                   // 4 VMEM (oldest)
    __builtin_amdgcn_sched_barrier(0);
    #pragma unroll
    for (int k = 0; k < 2; ++k) af[k] = *(const short8*)(ap + k * 32);  // 2 newest
    __builtin_amdgcn_sched_barrier(0);
    BARRIER_CNT2();                                // stage(0) visible; A(0) in flight

    f32x4 acc[8] = {};
    for (int c = 0; c < 18; ++c) {
        int cur = c & 1;
        if (c < 17) {
            STAGE(cur ^ 1, c + 1);                 // 4 VMEM
            __builtin_amdgcn_sched_barrier(0);
            #pragma unroll
            for (int k = 0; k < 2; ++k)            // 2 VMEM (newest before wait)
                afn[k] = *(const short8*)(ap + ((c + 1) * 2 + k) * 32);
            __builtin_amdgcn_sched_barrier(0);
        }
        __builtin_amdgcn_s_setprio(1);
        #pragma unroll
        for (int k = 0; k < 2; ++k) {
            #pragma unroll
            for (int t = 0; t < 8; ++t) {
                short8 b = Bs[cur][k * 512 + t * 64 + lane];
                acc[t] = __builtin_amdgcn_mfma_f32_16x16x32_bf16(af[k], b, acc[t], 0, 0, 0);
            }
        }
        __builtin_amdgcn_s_setprio(0);
        if (c < 17) {
            BARRIER_CNT2();                        // drain stage(c+1); A(c+1) flies on
            af[0] = afn[0]; af[1] = afn[1];
        }
    }
    #undef STAGE
    #undef BARRIER_CNT2

    float bcol[8];
    #pragma unroll
    for (int t = 0; t < 8; ++t) bcol[t] = bias[t * 16 + l15];

    if (MODE == 0) {
        float gcol[8], lbcol[8];
        #pragma unroll
        for (int t = 0; t < 8; ++t) { gcol[t] = lng[t * 16 + l15]; lbcol[t] = lnb[t * 16 + l15]; }
        #pragma unroll
        for (int reg = 0; reg < 4; ++reg) {
            int row = m0 + lhi * 4 + reg;
            float tv[8];
            float s = 0.f;
            #pragma unroll
            for (int t = 0; t < 8; ++t) { tv[t] = acc[t][reg] + bcol[t]; s += tv[t]; }
            #pragma unroll
            for (int msk = 1; msk < 16; msk <<= 1) s += __shfl_xor(s, msk);
            float mu = s * (1.0f / 128.0f);
            float q = 0.f;
            #pragma unroll
            for (int t = 0; t < 8; ++t) { float d = tv[t] - mu; q += d * d; }
            #pragma unroll
            for (int msk = 1; msk < 16; msk <<= 1) q += __shfl_xor(q, msk);
            float rs = rsqrtf(q * (1.0f / 128.0f) + 1e-5f);
            if (row < N) {
                #pragma unroll
                for (int t = 0; t < 8; ++t) {
                    float u = gelu_exact((tv[t] - mu) * rs * gcol[t] + lbcol[t]);
                    A[(size_t)row * LDA + 1024 + t * 16 + l15] = f2bf(u);
                }
            }
        }
    } else {
        #pragma unroll
        for (int reg = 0; reg < 4; ++reg) {
            int row = m0 + lhi * 4 + reg;
            if (row < N) {
                #pragma unroll
                for (int t = 0; t < 8; ++t) {
                    size_t idx = (size_t)row * 128 + t * 16 + l15;
                    outp[idx] = acc[t][reg] + bcol[t] + xres[idx];
                }
            }
        }
    }
}

extern "C" void kernel_launch(void* const* d_in, const int* in_sizes, int n_in,
                              void* d_out, int out_size, void* d_ws, size_t ws_size,
                              hipStream_t stream) {
    const float* x     = (const float*)d_in[0];
    const int*   ei    = (const int*)d_in[1];
    const float* attr  = (const float*)d_in[2];
    const float* ln1g  = (const float*)d_in[3];
    const float* ln1b  = (const float*)d_in[4];
    const float* W1    = (const float*)d_in[5];
    const float* root1 = (const float*)d_in[6];
    const float* b1    = (const float*)d_in[7];
    const float* ln2g  = (const float*)d_in[8];
    const float* ln2b  = (const float*)d_in[9];
    const float* W2    = (const float*)d_in[10];
    const float* root2 = (const float*)d_in[11];
    const float* b2    = (const float*)d_in[12];

    const int N = in_sizes[0] / 128;   // 50000
    const int E = in_sizes[1] / 2;     // 600000

    // workspace layout; A padded to 50048 rows (782 blocks x 64) for OOB-safe
    // A-frag reads in the last GEMM block. 50048*1152*2 = 115,310,592 B.
    char* ws = (char*)d_ws;
    unsigned short* A     = (unsigned short*)(ws);                    // 115,310,592
    unsigned short* Bf1   = (unsigned short*)(ws + 115400000);        // 294,912
    unsigned short* Bf2   = (unsigned short*)(ws + 115700000);        // 294,912
    int*            cnt   = (int*)(ws + 116000000);                   // 200,704
    int*            part  = (int*)(ws + 116210000);                   // 200,704
    int*            bsum  = (int*)(ws + 116420000);                   // 1,024
    int*            rowptr= (int*)(ws + 116430000);                   // 200,000
    int*            woff  = (int*)(ws + 116640000);                   // 200,000
    int*            esrc  = (int*)(ws + 116850000);                   // 2,400,000
    short8*         eattr = (short8*)(ws + 119250000);                // 9,600,000

    const int scanBlocks  = (N + 255) / 256;               // 196
    const int edgeBlocksE = (E + 255) / 256;               // 2344
    const int rowsBlocks  = (N * 64 + 255) / 256;          // 12500
    const int nodeBlocks  = (N + 3) / 4;                   // 12500
    const int gemmBlocks  = (N + 63) / 64;                 // 782
    const int prepBlocks  = 1152 + scanBlocks + rowsBlocks; // pack + zero + ln_gelu

    // pack weights + zero histogram + layer-1 LN/GELU, one dispatch
    prep_all<<<prepBlocks, 256, 0, stream>>>(W1, root1, Bf1, W2, root2, Bf2,
                                             cnt, scanBlocks,
                                             x, ln1g, ln1b, A, N);

    // CSR build (by dst)
    hist_dst<<<edgeBlocksE, 256, 0, stream>>>(ei, cnt, E);
    scan1<<<scanBlocks, 256, 0, stream>>>(cnt, part, bsum, N);
    scan3<<<scanBlocks, 256, 0, stream>>>(part, bsum, rowptr, woff, N);
    scatter_edges<<<edgeBlocksE, 256, 0, stream>>>(ei, (const float4*)attr, woff, esrc, eattr, E);

    // ---- layer 1 ----
    edge_z<<<nodeBlocks, 256, 0, stream>>>(rowptr, esrc, eattr, A, N, E);
    gemm_fused<0><<<gemmBlocks, 256, 0, stream>>>(A, Bf1, b1, ln2g, ln2b, nullptr, nullptr, N);

    // ---- layer 2 ----
    edge_z<<<nodeBlocks, 256, 0, stream>>>(rowptr, esrc, eattr, A, N, E);
    gemm_fused<1><<<gemmBlocks, 256, 0, stream>>>(A, Bf2, b2, nullptr, nullptr, x, (float*)d_out, N);
}